// Round 1
// baseline (408.736 us; speedup 1.0000x reference)
//
#include <hip/hip_runtime.h>

typedef __bf16 bf16x8 __attribute__((ext_vector_type(8)));
typedef float f32x4 __attribute__((ext_vector_type(4)));
typedef unsigned short u16;

#define NN 10000
#define NE 640000
#define DIM 128
#define TD 64
#define LDA 328   // bf16 elements per row of the K=320 staging tile (pad 8)
#define LDX 136   // bf16 elements per row of the K=128 tiles (pad 8)

__device__ __forceinline__ u16 f2bf(float f){
    union { float f; unsigned u; } v; v.f = f;
    unsigned r = v.u + 0x7fffu + ((v.u >> 16) & 1u);
    return (u16)(r >> 16);
}
__device__ __forceinline__ float silu_f(float x){ return x / (1.0f + __expf(-x)); }

// ---------------- weight prep: fp32 -> bf16 transposed [j][k] ----------------
// eW1t[j][k] : k<256 -> eW1[k][j]; k>=256 -> eW1[k+1][j] (row 256 = dist handled separately)
__global__ __launch_bounds__(256) void prep_weights(
    const float* __restrict__ eW1, const float* __restrict__ nW1,
    const float* __restrict__ eW2, const float* __restrict__ cW1,
    const float* __restrict__ nW2,
    u16* __restrict__ eW1t, u16* __restrict__ nW1t,
    u16* __restrict__ eW2t, u16* __restrict__ cW1t, u16* __restrict__ nW2t)
{
    int i = blockIdx.x * 256 + threadIdx.x;
    if (i < 40960) {                       // eW1t [128][320]
        int j = i / 320, k = i - j * 320;
        int r = (k < 256) ? k : k + 1;
        eW1t[i] = f2bf(eW1[r * DIM + j]);
    } else if (i < 81920) {                // nW1t [128][320]
        int t = i - 40960;
        int j = t / 320, k = t - j * 320;
        nW1t[t] = f2bf(nW1[k * DIM + j]);
    } else if (i < 98304) {                // eW2t [128][128]
        int t = i - 81920;
        int j = t >> 7, k = t & 127;
        eW2t[t] = f2bf(eW2[k * DIM + j]);
    } else if (i < 114688) {               // cW1t [128][128]
        int t = i - 98304;
        int j = t >> 7, k = t & 127;
        cW1t[t] = f2bf(cW1[k * DIM + j]);
    } else if (i < 131072) {               // nW2t [128][128]
        int t = i - 114688;
        int j = t >> 7, k = t & 127;
        nW2t[t] = f2bf(nW2[k * DIM + j]);
    }
}

// ---------------- edge kernel: 64 edges per block, 4 waves ----------------
__global__ __launch_bounds__(256) void egnn_edge(
    const float* __restrict__ h, const float* __restrict__ diff_cart,
    const float* __restrict__ dist_sq, const int* __restrict__ esrc,
    const int* __restrict__ edst, const float* __restrict__ tembE,
    const float* __restrict__ eW1, const float* __restrict__ eb1,
    const float* __restrict__ eb2, const float* __restrict__ cb1,
    const float* __restrict__ cW2,
    const u16* __restrict__ eW1t, const u16* __restrict__ eW2t,
    const u16* __restrict__ cW1t,
    float* __restrict__ m_i, float* __restrict__ coord_out)
{
    __shared__ u16 Abuf[64 * LDA];     // K=320 edge-feature tile; reused as Mbuf [64][LDX]
    __shared__ u16 Xbuf[64 * LDX];     // intermediate bf16 tile
    __shared__ int srcv[64], dstv[64];
    __shared__ float distv[64];
    __shared__ float cwpart[4][64];

    const int tid  = threadIdx.x;
    const int lane = tid & 63;
    const int w    = tid >> 6;
    const int lo   = lane & 15, hi = lane >> 4;
    const int ebase = blockIdx.x * 64;

    if (tid < 64) {
        srcv[tid]  = esrc[ebase + tid];
        dstv[tid]  = edst[ebase + tid];
        distv[tid] = dist_sq[ebase + tid];
    }
    __syncthreads();

    // ---- stage edge features -> bf16 LDS tile [64][320] (+pad) ----
    #pragma unroll
    for (int it = 0; it < 8; ++it) {           // h[src] -> cols 0..127
        int f = it * 256 + tid, e = f >> 5, c = f & 31;
        float4 v = *reinterpret_cast<const float4*>(h + (size_t)srcv[e] * DIM + c * 4);
        unsigned p0 = (unsigned)f2bf(v.x) | ((unsigned)f2bf(v.y) << 16);
        unsigned p1 = (unsigned)f2bf(v.z) | ((unsigned)f2bf(v.w) << 16);
        *reinterpret_cast<uint2*>(&Abuf[e * LDA + c * 4]) = make_uint2(p0, p1);
    }
    #pragma unroll
    for (int it = 0; it < 8; ++it) {           // h[dst] -> cols 128..255
        int f = it * 256 + tid, e = f >> 5, c = f & 31;
        float4 v = *reinterpret_cast<const float4*>(h + (size_t)dstv[e] * DIM + c * 4);
        unsigned p0 = (unsigned)f2bf(v.x) | ((unsigned)f2bf(v.y) << 16);
        unsigned p1 = (unsigned)f2bf(v.z) | ((unsigned)f2bf(v.w) << 16);
        *reinterpret_cast<uint2*>(&Abuf[e * LDA + 128 + c * 4]) = make_uint2(p0, p1);
    }
    #pragma unroll
    for (int it = 0; it < 4; ++it) {           // t_emb -> cols 256..319
        int f = it * 256 + tid, e = f >> 4, c = f & 15;
        float4 v = *reinterpret_cast<const float4*>(tembE + (size_t)(ebase + e) * TD + c * 4);
        unsigned p0 = (unsigned)f2bf(v.x) | ((unsigned)f2bf(v.y) << 16);
        unsigned p1 = (unsigned)f2bf(v.z) | ((unsigned)f2bf(v.w) << 16);
        *reinterpret_cast<uint2*>(&Abuf[e * LDA + 256 + c * 4]) = make_uint2(p0, p1);
    }
    __syncthreads();

    const int colb = w * 32;                   // wave owns cols [colb, colb+32)
    f32x4 acc[4][2];

    // ---- GEMM1: [64x320] @ eW1t -> x1, + eb1 + dist*w1d, SiLU -> Xbuf ----
    #pragma unroll
    for (int rt = 0; rt < 4; ++rt)
        #pragma unroll
        for (int n = 0; n < 2; ++n) acc[rt][n] = f32x4{0.f, 0.f, 0.f, 0.f};
    for (int ks = 0; ks < 10; ++ks) {
        bf16x8 a[4], b[2];
        #pragma unroll
        for (int rt = 0; rt < 4; ++rt)
            a[rt] = *reinterpret_cast<const bf16x8*>(&Abuf[(rt * 16 + lo) * LDA + ks * 32 + hi * 8]);
        #pragma unroll
        for (int n = 0; n < 2; ++n)
            b[n] = *reinterpret_cast<const bf16x8*>(&eW1t[(colb + n * 16 + lo) * 320 + ks * 32 + hi * 8]);
        #pragma unroll
        for (int rt = 0; rt < 4; ++rt)
            #pragma unroll
            for (int n = 0; n < 2; ++n)
                acc[rt][n] = __builtin_amdgcn_mfma_f32_16x16x32_bf16(a[rt], b[n], acc[rt][n], 0, 0, 0);
    }
    {
        const float* w1d = eW1 + 256 * DIM;    // dist row of eW1 (contiguous)
        float bias1[2], wd[2];
        #pragma unroll
        for (int n = 0; n < 2; ++n) { int col = colb + n * 16 + lo; bias1[n] = eb1[col]; wd[n] = w1d[col]; }
        #pragma unroll
        for (int rt = 0; rt < 4; ++rt)
            #pragma unroll
            for (int n = 0; n < 2; ++n)
                #pragma unroll
                for (int r = 0; r < 4; ++r) {
                    int row = rt * 16 + hi * 4 + r;
                    float x = acc[rt][n][r] + bias1[n] + distv[row] * wd[n];
                    Xbuf[row * LDX + colb + n * 16 + lo] = f2bf(silu_f(x));
                }
    }
    __syncthreads();

    // ---- GEMM2: x1b @ eW2t + eb2, SiLU -> m_ij (Mbuf + atomic scatter) ----
    #pragma unroll
    for (int rt = 0; rt < 4; ++rt)
        #pragma unroll
        for (int n = 0; n < 2; ++n) acc[rt][n] = f32x4{0.f, 0.f, 0.f, 0.f};
    for (int ks = 0; ks < 4; ++ks) {
        bf16x8 a[4], b[2];
        #pragma unroll
        for (int rt = 0; rt < 4; ++rt)
            a[rt] = *reinterpret_cast<const bf16x8*>(&Xbuf[(rt * 16 + lo) * LDX + ks * 32 + hi * 8]);
        #pragma unroll
        for (int n = 0; n < 2; ++n)
            b[n] = *reinterpret_cast<const bf16x8*>(&eW2t[(colb + n * 16 + lo) * 128 + ks * 32 + hi * 8]);
        #pragma unroll
        for (int rt = 0; rt < 4; ++rt)
            #pragma unroll
            for (int n = 0; n < 2; ++n)
                acc[rt][n] = __builtin_amdgcn_mfma_f32_16x16x32_bf16(a[rt], b[n], acc[rt][n], 0, 0, 0);
    }
    {
        float bias2[2];
        #pragma unroll
        for (int n = 0; n < 2; ++n) bias2[n] = eb2[colb + n * 16 + lo];
        #pragma unroll
        for (int rt = 0; rt < 4; ++rt)
            #pragma unroll
            for (int n = 0; n < 2; ++n)
                #pragma unroll
                for (int r = 0; r < 4; ++r) {
                    int row = rt * 16 + hi * 4 + r;
                    int col = colb + n * 16 + lo;
                    float mv = silu_f(acc[rt][n][r] + bias2[n]);
                    Abuf[row * LDX + col] = f2bf(mv);   // Mbuf (Abuf free after GEMM1)
                    unsafeAtomicAdd(m_i + (size_t)dstv[row] * DIM + col, mv);
                }
    }
    __syncthreads();

    // ---- GEMM3: m_b @ cW1t + cb1, SiLU, dot cW2 -> coord_w ----
    #pragma unroll
    for (int rt = 0; rt < 4; ++rt)
        #pragma unroll
        for (int n = 0; n < 2; ++n) acc[rt][n] = f32x4{0.f, 0.f, 0.f, 0.f};
    for (int ks = 0; ks < 4; ++ks) {
        bf16x8 a[4], b[2];
        #pragma unroll
        for (int rt = 0; rt < 4; ++rt)
            a[rt] = *reinterpret_cast<const bf16x8*>(&Abuf[(rt * 16 + lo) * LDX + ks * 32 + hi * 8]);
        #pragma unroll
        for (int n = 0; n < 2; ++n)
            b[n] = *reinterpret_cast<const bf16x8*>(&cW1t[(colb + n * 16 + lo) * 128 + ks * 32 + hi * 8]);
        #pragma unroll
        for (int rt = 0; rt < 4; ++rt)
            #pragma unroll
            for (int n = 0; n < 2; ++n)
                acc[rt][n] = __builtin_amdgcn_mfma_f32_16x16x32_bf16(a[rt], b[n], acc[rt][n], 0, 0, 0);
    }
    {
        float bias3[2], cw2c[2];
        #pragma unroll
        for (int n = 0; n < 2; ++n) { int col = colb + n * 16 + lo; bias3[n] = cb1[col]; cw2c[n] = cW2[col]; }
        #pragma unroll
        for (int rt = 0; rt < 4; ++rt)
            #pragma unroll
            for (int r = 0; r < 4; ++r) {
                float p = silu_f(acc[rt][0][r] + bias3[0]) * cw2c[0]
                        + silu_f(acc[rt][1][r] + bias3[1]) * cw2c[1];
                p += __shfl_xor(p, 1, 16);
                p += __shfl_xor(p, 2, 16);
                p += __shfl_xor(p, 4, 16);
                p += __shfl_xor(p, 8, 16);
                if (lo == 0) cwpart[w][rt * 16 + hi * 4 + r] = p;
            }
    }
    __syncthreads();

    // ---- coord scatter: 3 atomics per edge ----
    if (tid < 192) {
        int e = tid / 3, c = tid - e * 3;
        float cw = cwpart[0][e] + cwpart[1][e] + cwpart[2][e] + cwpart[3][e];
        float val = diff_cart[(size_t)(ebase + e) * 3 + c] * cw;
        unsafeAtomicAdd(coord_out + (size_t)srcv[e] * 3 + c, val);
    }
}

// ---------------- node kernel: 64 nodes per block ----------------
__global__ __launch_bounds__(256) void egnn_node(
    const float* __restrict__ h, const float* __restrict__ m_i,
    const float* __restrict__ tembN,
    const float* __restrict__ nb1, const float* __restrict__ nb2,
    const u16* __restrict__ nW1t, const u16* __restrict__ nW2t,
    float* __restrict__ out)
{
    __shared__ u16 Abuf[64 * LDA];
    __shared__ u16 Xbuf[64 * LDX];

    const int tid  = threadIdx.x;
    const int lane = tid & 63;
    const int w    = tid >> 6;
    const int lo   = lane & 15, hi = lane >> 4;
    const int nbase = blockIdx.x * 64;

    // ---- stage node features [h | m_i | t_emb] ----
    #pragma unroll
    for (int it = 0; it < 8; ++it) {
        int f = it * 256 + tid, e = f >> 5, c = f & 31;
        int node = nbase + e; if (node >= NN) node = NN - 1;
        float4 v = *reinterpret_cast<const float4*>(h + (size_t)node * DIM + c * 4);
        unsigned p0 = (unsigned)f2bf(v.x) | ((unsigned)f2bf(v.y) << 16);
        unsigned p1 = (unsigned)f2bf(v.z) | ((unsigned)f2bf(v.w) << 16);
        *reinterpret_cast<uint2*>(&Abuf[e * LDA + c * 4]) = make_uint2(p0, p1);
        float4 v2 = *reinterpret_cast<const float4*>(m_i + (size_t)node * DIM + c * 4);
        unsigned q0 = (unsigned)f2bf(v2.x) | ((unsigned)f2bf(v2.y) << 16);
        unsigned q1 = (unsigned)f2bf(v2.z) | ((unsigned)f2bf(v2.w) << 16);
        *reinterpret_cast<uint2*>(&Abuf[e * LDA + 128 + c * 4]) = make_uint2(q0, q1);
    }
    #pragma unroll
    for (int it = 0; it < 4; ++it) {
        int f = it * 256 + tid, e = f >> 4, c = f & 15;
        int node = nbase + e; if (node >= NN) node = NN - 1;
        float4 v = *reinterpret_cast<const float4*>(tembN + (size_t)node * TD + c * 4);
        unsigned p0 = (unsigned)f2bf(v.x) | ((unsigned)f2bf(v.y) << 16);
        unsigned p1 = (unsigned)f2bf(v.z) | ((unsigned)f2bf(v.w) << 16);
        *reinterpret_cast<uint2*>(&Abuf[e * LDA + 256 + c * 4]) = make_uint2(p0, p1);
    }
    __syncthreads();

    const int colb = w * 32;
    f32x4 acc[4][2];

    // ---- GEMM1: K=320 with nW1t, + nb1, SiLU -> Xbuf ----
    #pragma unroll
    for (int rt = 0; rt < 4; ++rt)
        #pragma unroll
        for (int n = 0; n < 2; ++n) acc[rt][n] = f32x4{0.f, 0.f, 0.f, 0.f};
    for (int ks = 0; ks < 10; ++ks) {
        bf16x8 a[4], b[2];
        #pragma unroll
        for (int rt = 0; rt < 4; ++rt)
            a[rt] = *reinterpret_cast<const bf16x8*>(&Abuf[(rt * 16 + lo) * LDA + ks * 32 + hi * 8]);
        #pragma unroll
        for (int n = 0; n < 2; ++n)
            b[n] = *reinterpret_cast<const bf16x8*>(&nW1t[(colb + n * 16 + lo) * 320 + ks * 32 + hi * 8]);
        #pragma unroll
        for (int rt = 0; rt < 4; ++rt)
            #pragma unroll
            for (int n = 0; n < 2; ++n)
                acc[rt][n] = __builtin_amdgcn_mfma_f32_16x16x32_bf16(a[rt], b[n], acc[rt][n], 0, 0, 0);
    }
    {
        float bias1[2];
        #pragma unroll
        for (int n = 0; n < 2; ++n) bias1[n] = nb1[colb + n * 16 + lo];
        #pragma unroll
        for (int rt = 0; rt < 4; ++rt)
            #pragma unroll
            for (int n = 0; n < 2; ++n)
                #pragma unroll
                for (int r = 0; r < 4; ++r) {
                    int row = rt * 16 + hi * 4 + r;
                    Xbuf[row * LDX + colb + n * 16 + lo] = f2bf(silu_f(acc[rt][n][r] + bias1[n]));
                }
    }
    __syncthreads();

    // ---- GEMM2: K=128 with nW2t, + nb2 + h residual -> out ----
    #pragma unroll
    for (int rt = 0; rt < 4; ++rt)
        #pragma unroll
        for (int n = 0; n < 2; ++n) acc[rt][n] = f32x4{0.f, 0.f, 0.f, 0.f};
    for (int ks = 0; ks < 4; ++ks) {
        bf16x8 a[4], b[2];
        #pragma unroll
        for (int rt = 0; rt < 4; ++rt)
            a[rt] = *reinterpret_cast<const bf16x8*>(&Xbuf[(rt * 16 + lo) * LDX + ks * 32 + hi * 8]);
        #pragma unroll
        for (int n = 0; n < 2; ++n)
            b[n] = *reinterpret_cast<const bf16x8*>(&nW2t[(colb + n * 16 + lo) * 128 + ks * 32 + hi * 8]);
        #pragma unroll
        for (int rt = 0; rt < 4; ++rt)
            #pragma unroll
            for (int n = 0; n < 2; ++n)
                acc[rt][n] = __builtin_amdgcn_mfma_f32_16x16x32_bf16(a[rt], b[n], acc[rt][n], 0, 0, 0);
    }
    {
        float bias2[2];
        #pragma unroll
        for (int n = 0; n < 2; ++n) bias2[n] = nb2[colb + n * 16 + lo];
        #pragma unroll
        for (int rt = 0; rt < 4; ++rt)
            #pragma unroll
            for (int n = 0; n < 2; ++n)
                #pragma unroll
                for (int r = 0; r < 4; ++r) {
                    int row = rt * 16 + hi * 4 + r;
                    int node = nbase + row;
                    if (node < NN) {
                        int col = colb + n * 16 + lo;
                        out[(size_t)node * DIM + col] =
                            acc[rt][n][r] + bias2[n] + h[(size_t)node * DIM + col];
                    }
                }
    }
}

extern "C" void kernel_launch(void* const* d_in, const int* in_sizes, int n_in,
                              void* d_out, int out_size, void* d_ws, size_t ws_size,
                              hipStream_t stream)
{
    const float* h     = (const float*)d_in[0];
    const float* diffc = (const float*)d_in[1];
    const float* dist  = (const float*)d_in[2];
    const int*   esrc  = (const int*)d_in[3];
    const int*   edst  = (const int*)d_in[4];
    const float* tembE = (const float*)d_in[5];
    const float* tembN = (const float*)d_in[6];
    const float* eW1   = (const float*)d_in[7];
    const float* eb1   = (const float*)d_in[8];
    const float* eW2   = (const float*)d_in[9];
    const float* eb2   = (const float*)d_in[10];
    const float* cW1   = (const float*)d_in[11];
    const float* cb1   = (const float*)d_in[12];
    const float* cW2   = (const float*)d_in[13];
    const float* nW1   = (const float*)d_in[14];
    const float* nb1   = (const float*)d_in[15];
    const float* nW2   = (const float*)d_in[16];
    const float* nb2   = (const float*)d_in[17];

    char* ws = (char*)d_ws;
    float* m_i  = (float*)(ws + 0);               // 10000*128*4 = 5,120,000 B
    u16* eW1t   = (u16*)(ws + 5120000);           // 81,920 B
    u16* eW2t   = (u16*)(ws + 5201920);           // 32,768 B
    u16* cW1t   = (u16*)(ws + 5234688);           // 32,768 B
    u16* nW1t   = (u16*)(ws + 5267456);           // 81,920 B
    u16* nW2t   = (u16*)(ws + 5349376);           // 32,768 B -> total 5,382,144 B

    float* outp      = (float*)d_out;
    float* coord_out = outp + (size_t)NN * DIM;

    hipMemsetAsync(d_out, 0, (size_t)out_size * sizeof(float), stream);
    hipMemsetAsync(m_i, 0, (size_t)NN * DIM * sizeof(float), stream);

    prep_weights<<<512, 256, 0, stream>>>(eW1, nW1, eW2, cW1, nW2,
                                          eW1t, nW1t, eW2t, cW1t, nW2t);
    egnn_edge<<<NE / 64, 256, 0, stream>>>(h, diffc, dist, esrc, edst, tembE,
                                           eW1, eb1, eb2, cb1, cW2,
                                           eW1t, eW2t, cW1t, m_i, coord_out);
    egnn_node<<<(NN + 63) / 64, 256, 0, stream>>>(h, m_i, tembN, nb1, nb2,
                                                  nW1t, nW2t, outp);
}